// Round 15
// baseline (429.764 us; speedup 1.0000x reference)
//
#include <hip/hip_runtime.h>
#include <math.h>

// Problem constants (from reference)
#define N_    128
#define T_    1000
#define NS_   10
#define NO_   10
#define HID_  64
#define DENSE_ 32

typedef float v2f __attribute__((ext_vector_type(2)));
typedef float v4f __attribute__((ext_vector_type(4)));
typedef _Float16 h2v __attribute__((ext_vector_type(2)));

// Barrier that waits only on LDS ops (global h_out stores are consumed by a
// later dispatch, never by another wave in-kernel -> no vmcnt drain).
#define LDS_BARRIER() asm volatile("s_waitcnt lgkmcnt(0)\n\ts_barrier" ::: "memory")

// f16 dot2: acc += a[0]*b[0] + a[1]*b[1]  (v_dot2_f32_f16)
#if __has_builtin(__builtin_amdgcn_fdot2)
#define FDOT2(acc, a, b) (acc) = __builtin_amdgcn_fdot2((a), (b), (acc), false)
#else
#define FDOT2(acc, a, b) asm("v_dot2_f32_f16 %0, %1, %2, %0" : "+v"(acc) : "v"(a), "v"(b))
#endif

// pack two f32 -> 2x f16 (v_cvt_pkrtz_f16_f32), bit-cast to our h2v type
__device__ __forceinline__ h2v pk_f16(float a, float b) {
    return __builtin_bit_cast(h2v, __builtin_amdgcn_cvt_pkrtz(a, b));
}

// intra-quad DPP exchange (ctrl is a compile-time immediate)
template <int CTRL>
__device__ __forceinline__ float dpp_mov(float x) {
    int r = __builtin_amdgcn_update_dpp(0, __builtin_bit_cast(int, x),
                                        CTRL, 0xF, 0xF, true);
    return __builtin_bit_cast(float, r);
}
// sum over the 4 lanes of a quad; all 4 lanes get the full sum
__device__ __forceinline__ float quad_sum(float x) {
    x += dpp_mov<0xB1>(x);   // quad_perm [1,0,3,2]
    x += dpp_mov<0x4E>(x);   // quad_perm [2,3,0,1]
    return x;
}

__device__ __forceinline__ float fast_sigmoid(float x) {
    return __builtin_amdgcn_rcpf(1.f + __expf(-x));   // NaN-safe
}
__device__ __forceinline__ float fast_tanh(float x) {
    float e = __expf(2.f * x);
    return 1.f - 2.f * __builtin_amdgcn_rcpf(e + 1.f); // NaN-safe
}

// ---------------------------------------------------------------------------
// Phase 1: GRU scan. TWO samples per block as separate wave-groups:
// waves 0-3 = sample A, waves 4-7 = sample B (512 threads, 64 blocks).
// Each SIMD hosts one A-wave + one B-wave; the CU scheduler issues one
// sample's dots during the other's trans/LDS/barrier stalls (r14 was 1
// wave/SIMD -> ~60% exposed latency; r10's failure was 2 samples inside ONE
// wave's issue stream, which serializes instead).
// Within a sample: lane QUAD owns hidden unit (unit = w*16 + l>>4... l>>2),
// kh = l&3 covers 16 K-elems; 29 pinned f16 weight regs/lane (r13-proven).
// Whole-sample Y staged to LDS f16 up front (r14-proven); loop has zero
// global loads. One LDS-only barrier per step (syncs both samples -> benign
// lockstep, identical work). Block 0 tid 0 initializes out[0].
// ---------------------------------------------------------------------------
__global__ __launch_bounds__(512, 2) void gru_kernel(
    const float* __restrict__ Y,     // (N,T,NO)
    const float* __restrict__ W_ih,  // (192,10)
    const float* __restrict__ W_hh,  // (192,64)
    const float* __restrict__ b_ih,
    const float* __restrict__ b_hh,
    float* __restrict__ h_out,       // (N*T,64)
    float* __restrict__ out)
{
    const int tid  = threadIdx.x;    // 0..511
    const int sid  = tid >> 8;       // sample slot 0/1
    const int t8   = tid & 255;      // index within sample group
    const int w    = t8 >> 6;        // wave-in-sample 0..3
    const int l    = t8 & 63;
    const int unit = w * 16 + (l >> 2);  // hidden unit 0..63
    const int kh   = l & 3;              // K quarter
    const int n    = 2 * blockIdx.x + sid;

    if (n == 0 && tid == 0)
        out[0] = 0.5f * (float)NS_ * (float)T_ * logf(2.f * 3.14159265358979323846f);

    // --- LDS: full-sample y (f16) per slot + hidden states ---
    __shared__ __align__(16) h2v ylds[2][T_ * NO_ / 2];   // 2 x 20 KB
    __shared__ __align__(16) _Float16 hbuf[2][HID_];

    const float* Yn = Y + (size_t)n * T_ * NO_;
    // stage Y: each sample's 256 threads do coalesced float2 loads -> f16
    {
        const v2f* src = (const v2f*)Yn;
#pragma unroll 4
        for (int i = t8; i < T_ * NO_ / 2; i += 256) {
            v2f v = src[i];
            ylds[sid][i] = pk_f16(v[0], v[1]);
        }
    }

    // --- W_hh: 3 gate rows, own K-quarter (16 f32 -> 8 h2v each) ---
    h2v whh[3][8];
#pragma unroll
    for (int g = 0; g < 3; ++g) {
        const v4f* wp = (const v4f*)(W_hh + (size_t)(g * HID_ + unit) * HID_ + kh * 16);
#pragma unroll
        for (int q = 0; q < 4; ++q) {
            v4f t = wp[q];
            whh[g][2 * q]     = pk_f16(t.x, t.y);
            whh[g][2 * q + 1] = pk_f16(t.z, t.w);
        }
    }
    // --- W_ih: full row of gate kh (kh==3: zero-scaled duplicate of gate 2) ---
    h2v wihx[5];
    {
        const float s = (kh == 3) ? 0.f : 1.f;
        const int gx = (kh < 3) ? kh : 2;
        const v2f* ip = (const v2f*)(W_ih + (size_t)(gx * HID_ + unit) * NO_);
#pragma unroll
        for (int i = 0; i < 5; ++i) { v2f t = ip[i]; wihx[i] = pk_f16(t[0] * s, t[1] * s); }
    }
    // VOLATILE pin: loads stay in the preamble, values stay resident.
#pragma unroll
    for (int g = 0; g < 3; ++g)
#pragma unroll
        for (int k = 0; k < 8; ++k) asm volatile("" : "+v"(whh[g][k]));
#pragma unroll
    for (int i = 0; i < 5; ++i) asm volatile("" : "+v"(wihx[i]));

    // x-routing masks (kh-fixed) and bias-folded accumulator inits
    const float mR = (kh == 0) ? 1.f : 0.f;
    const float mZ = (kh == 1) ? 1.f : 0.f;
    const float mN = (kh >= 2) ? 1.f : 0.f;
    const float cR = (kh == 0) ? (b_ih[unit] + b_hh[unit]) : 0.f;
    const float cZ = (kh == 0) ? (b_ih[HID_ + unit] + b_hh[HID_ + unit]) : 0.f;
    const float cN = (kh == 0) ? b_hh[2 * HID_ + unit] : 0.f;
    const float cX = (kh == 0) ? b_ih[2 * HID_ + unit] : 0.f;

    if (t8 < HID_) hbuf[sid][t8] = (_Float16)0.f;
    float h_own = 0.f;
    __syncthreads();   // staging + hbuf visible to all waves

    float* hout = h_out + (size_t)n * T_ * HID_ + unit;
    const h2v* yls = ylds[sid];
    const _Float16* hb = hbuf[sid];

    // prologue: y row 0 into registers (uniform LDS reads)
    h2v y0 = yls[0], y1 = yls[1], y2 = yls[2], y3 = yls[3], y4 = yls[4];

    for (int t = 0; t < T_; ++t) {
        // x-projection from preloaded registers (overlaps hbuf read latency)
        float xs = 0.f;
        FDOT2(xs, wihx[0], y0); FDOT2(xs, wihx[1], y1); FDOT2(xs, wihx[2], y2);
        FDOT2(xs, wihx[3], y3); FDOT2(xs, wihx[4], y4);

        // h-projection: 2 uniform b128 reads of own K-quarter, 24 dot2
        float ar = cR, az = cZ, an = cN, xn = cX;
        const uint4* hp = (const uint4*)(hb + kh * 16);
        uint4 hq0 = hp[0], hq1 = hp[1];
        {
            h2v h0 = __builtin_bit_cast(h2v, hq0.x);
            h2v h1 = __builtin_bit_cast(h2v, hq0.y);
            h2v h2 = __builtin_bit_cast(h2v, hq0.z);
            h2v h3 = __builtin_bit_cast(h2v, hq0.w);
            FDOT2(ar, whh[0][0], h0); FDOT2(az, whh[1][0], h0); FDOT2(an, whh[2][0], h0);
            FDOT2(ar, whh[0][1], h1); FDOT2(az, whh[1][1], h1); FDOT2(an, whh[2][1], h1);
            FDOT2(ar, whh[0][2], h2); FDOT2(az, whh[1][2], h2); FDOT2(an, whh[2][2], h2);
            FDOT2(ar, whh[0][3], h3); FDOT2(az, whh[1][3], h3); FDOT2(an, whh[2][3], h3);
        }
        {
            h2v h0 = __builtin_bit_cast(h2v, hq1.x);
            h2v h1 = __builtin_bit_cast(h2v, hq1.y);
            h2v h2 = __builtin_bit_cast(h2v, hq1.z);
            h2v h3 = __builtin_bit_cast(h2v, hq1.w);
            FDOT2(ar, whh[0][4], h0); FDOT2(az, whh[1][4], h0); FDOT2(an, whh[2][4], h0);
            FDOT2(ar, whh[0][5], h1); FDOT2(az, whh[1][5], h1); FDOT2(an, whh[2][5], h1);
            FDOT2(ar, whh[0][6], h2); FDOT2(az, whh[1][6], h2); FDOT2(an, whh[2][6], h2);
            FDOT2(ar, whh[0][7], h3); FDOT2(az, whh[1][7], h3); FDOT2(an, whh[2][7], h3);
        }
        // route x into gate partials (3 fma; masks are lane constants)
        ar = fmaf(xs, mR, ar);
        az = fmaf(xs, mZ, az);
        xn = fmaf(xs, mN, xn);
        // quad combine (all 4 lanes end with full sums)
        ar = quad_sum(ar);
        az = quad_sum(az);
        an = quad_sum(an);
        xn = quad_sum(xn);
        // gates (lane-local, redundant across quad)
        const float r  = fast_sigmoid(ar);
        const float z  = fast_sigmoid(az);
        const float nn = fast_tanh(xn + r * an);
        const float h_new = nn + z * (h_own - nn);
        h_own = h_new;
        if (kh == 0) {
            hbuf[sid][unit] = (_Float16)h_new;  // next-step state (f16)
            hout[t * HID_] = h_new;             // fire-and-forget (f32)
        }
        // prefetch y row t+1 (uniform LDS reads; drained by barrier lgkmcnt)
        {
            const h2v* yrow = yls + 5 * ((t + 1 < T_) ? t + 1 : t);
            y0 = yrow[0]; y1 = yrow[1]; y2 = yrow[2]; y3 = yrow[3]; y4 = yrow[4];
        }
        LDS_BARRIER();
    }
}

// ---------------------------------------------------------------------------
// Phase 2: per-(n,t) dense head + information-form Kalman + log-pdf terms.
// Each block computes A = H^T inv(C_w), M = A H redundantly (parallel GJ).
// ---------------------------------------------------------------------------
__global__ __launch_bounds__(256) void post_kernel(
    const float* __restrict__ h_out,  // (N*T,64)
    const float* __restrict__ Y,      // (N,T,NO)
    const float* __restrict__ X,      // (N,T,NS)
    const float* __restrict__ Hm, const float* __restrict__ C_w,
    const float* __restrict__ W_fc, const float* __restrict__ b_fc,
    const float* __restrict__ W_mean, const float* __restrict__ b_mean,
    const float* __restrict__ W_vars, const float* __restrict__ b_vars,
    float* __restrict__ out)
{
    __shared__ float sWfc[DENSE_][HID_];
    __shared__ float sWm[NS_][DENSE_];
    __shared__ float sWv[NS_][DENSE_];
    __shared__ float sA[NS_][NO_];
    __shared__ float sM[NS_][NS_];
    __shared__ float sbfc[DENSE_], sbm[NS_], sbv[NS_];
    __shared__ float wsum[4];
    __shared__ float W[NO_][2 * NO_];
    __shared__ float fcol[NO_];

    const int tid = threadIdx.x;

    // --- per-block A, M via parallel Gauss-Jordan on C_w (10x10 SPD) ---
    if (tid < NO_ * NO_) {
        const int i = tid / NO_, jj = tid % NO_;
        W[i][jj] = C_w[tid];
        W[i][NO_ + jj] = (i == jj) ? 1.f : 0.f;
    }
    __syncthreads();
    for (int p = 0; p < NO_; ++p) {
        const float ip = 1.f / W[p][p];
        __syncthreads();
        if (tid < 2 * NO_) W[p][tid] *= ip;
        __syncthreads();
        if (tid < NO_) fcol[tid] = (tid == p) ? 0.f : W[tid][p];
        __syncthreads();
        if (tid < NO_ * 2 * NO_) {
            const int i = tid / (2 * NO_), jj = tid % (2 * NO_);
            W[i][jj] -= fcol[i] * W[p][jj];
        }
        __syncthreads();
    }
    if (tid < NS_ * NO_) {
        const int s = tid / NO_, o = tid % NO_;
        float acc = 0.f;
        for (int p = 0; p < NO_; ++p) acc += Hm[p * NS_ + s] * W[p][NO_ + o];
        sA[s][o] = acc;
    }
    __syncthreads();
    if (tid < NS_ * NS_) {
        const int s = tid / NS_, q = tid % NS_;
        float acc = 0.f;
        for (int o = 0; o < NO_; ++o) acc += sA[s][o] * Hm[o * NS_ + q];
        sM[s][q] = acc;
    }

    // --- stage dense-head weights ---
    for (int i = tid; i < DENSE_ * HID_; i += blockDim.x)
        sWfc[i / HID_][i % HID_] = W_fc[i];
    for (int i = tid; i < NS_ * DENSE_; i += blockDim.x) {
        sWm[i / DENSE_][i % DENSE_] = W_mean[i];
        sWv[i / DENSE_][i % DENSE_] = W_vars[i];
    }
    if (tid < DENSE_) sbfc[tid] = b_fc[tid];
    if (tid < NS_) { sbm[tid] = b_mean[tid]; sbv[tid] = b_vars[tid]; }
    __syncthreads();

    const int task = blockIdx.x * blockDim.x + tid;
    float contrib = 0.f;
    if (task < N_ * T_) {
        float y[DENSE_];
#pragma unroll
        for (int d = 0; d < DENSE_; ++d) y[d] = sbfc[d];
        const float* hp = h_out + (size_t)task * HID_;
#pragma unroll
        for (int k = 0; k < HID_; k += 4) {
            float4 h4 = *(const float4*)(hp + k);
#pragma unroll
            for (int d = 0; d < DENSE_; ++d) {
                y[d] += sWfc[d][k + 0] * h4.x + sWfc[d][k + 1] * h4.y +
                        sWfc[d][k + 2] * h4.z + sWfc[d][k + 3] * h4.w;
            }
        }
#pragma unroll
        for (int d = 0; d < DENSE_; ++d) y[d] = fmaxf(y[d], 0.f);

        float mu[NS_], vinv[NS_];
#pragma unroll
        for (int s = 0; s < NS_; ++s) {
            float am = sbm[s], av = sbv[s];
#pragma unroll
            for (int d = 0; d < DENSE_; ++d) { am += sWm[s][d] * y[d]; av += sWv[s][d] * y[d]; }
            mu[s] = am;
            float sp = (av > 20.f) ? av : log1pf(__expf(av));  // softplus
            vinv[s] = 1.f / sp;
        }

        const float* yo = Y + (size_t)task * NO_;
        const float* xo = X + (size_t)task * NS_;
        float b[NS_];
#pragma unroll
        for (int s = 0; s < NS_; ++s) {
            float acc = vinv[s] * mu[s];
#pragma unroll
            for (int o = 0; o < NO_; ++o) acc += sA[s][o] * yo[o];
            b[s] = acc;
        }

        // L_inv = M + diag(v^-1), Cholesky
        float L[NS_][NS_];
#pragma unroll
        for (int i = 0; i < NS_; ++i)
#pragma unroll
            for (int jj = 0; jj <= i; ++jj)
                L[i][jj] = sM[i][jj] + ((i == jj) ? vinv[i] : 0.f);
        float ld = 0.f;
        float dinv[NS_];
#pragma unroll
        for (int jj = 0; jj < NS_; ++jj) {
            float s = L[jj][jj];
#pragma unroll
            for (int k = 0; k < jj; ++k) s -= L[jj][k] * L[jj][k];
            float d = sqrtf(s);
            ld += __logf(d);
            float di = 1.f / d;
            dinv[jj] = di;
            L[jj][jj] = d;
#pragma unroll
            for (int i = jj + 1; i < NS_; ++i) {
                float t2 = L[i][jj];
#pragma unroll
                for (int k = 0; k < jj; ++k) t2 -= L[i][k] * L[jj][k];
                L[i][jj] = t2 * di;
            }
        }
        ld *= 2.f;

        float w[NS_];
#pragma unroll
        for (int i = 0; i < NS_; ++i) {
            float s = b[i];
#pragma unroll
            for (int k = 0; k < i; ++k) s -= L[i][k] * w[k];
            w[i] = s * dinv[i];
        }
        float mpost[NS_];
#pragma unroll
        for (int ii = NS_ - 1; ii >= 0; --ii) {
            float s = w[ii];
#pragma unroll
            for (int k = ii + 1; k < NS_; ++k) s -= L[k][ii] * mpost[k];
            mpost[ii] = s * dinv[ii];
        }

        float diff[NS_];
#pragma unroll
        for (int s = 0; s < NS_; ++s) diff[s] = xo[s] - mpost[s];
        float quad = 0.f;
#pragma unroll
        for (int jj = 0; jj < NS_; ++jj) {
            float u = 0.f;
#pragma unroll
            for (int i = jj; i < NS_; ++i) u += L[i][jj] * diff[i];
            quad += u * u;
        }

        contrib = 0.5f * (ld - quad) * (1.0f / (float)N_);
    }

#pragma unroll
    for (int off = 32; off; off >>= 1) contrib += __shfl_down(contrib, off);
    const int wid = tid >> 6;
    if ((tid & 63) == 0) wsum[wid] = contrib;
    __syncthreads();
    if (tid == 0) {
        float s = 0.f;
#pragma unroll
        for (int i = 0; i < 4; ++i) s += wsum[i];
        atomicAdd(out, s);
    }
}

// ---------------------------------------------------------------------------
extern "C" void kernel_launch(void* const* d_in, const int* in_sizes, int n_in,
                              void* d_out, int out_size, void* d_ws, size_t ws_size,
                              hipStream_t stream)
{
    const float* Y      = (const float*)d_in[0];
    const float* X      = (const float*)d_in[1];
    const float* H      = (const float*)d_in[2];
    const float* C_w    = (const float*)d_in[4];
    const float* W_ih   = (const float*)d_in[5];
    const float* W_hh   = (const float*)d_in[6];
    const float* b_ih   = (const float*)d_in[7];
    const float* b_hh   = (const float*)d_in[8];
    const float* W_fc   = (const float*)d_in[9];
    const float* b_fc   = (const float*)d_in[10];
    const float* W_mean = (const float*)d_in[11];
    const float* b_mean = (const float*)d_in[12];
    const float* W_vars = (const float*)d_in[13];
    const float* b_vars = (const float*)d_in[14];
    float* out = (float*)d_out;

    float* h_out = (float*)d_ws;                       // 32.77 MB

    hipLaunchKernelGGL(gru_kernel, dim3(N_ / 2), dim3(512), 0, stream,
                       Y, W_ih, W_hh, b_ih, b_hh, h_out, out);
    hipLaunchKernelGGL(post_kernel, dim3((N_ * T_ + 255) / 256), dim3(256), 0, stream,
                       h_out, Y, X, H, C_w, W_fc, b_fc, W_mean, b_mean,
                       W_vars, b_vars, out);
}

// Round 16
// 317.072 us; speedup vs baseline: 1.3554x; 1.3554x over previous
//
#include <hip/hip_runtime.h>
#include <math.h>

// Problem constants (from reference)
#define N_    128
#define T_    1000
#define NS_   10
#define NO_   10
#define HID_  64
#define DENSE_ 32

typedef float v2f __attribute__((ext_vector_type(2)));
typedef float v4f __attribute__((ext_vector_type(4)));
typedef _Float16 h2v __attribute__((ext_vector_type(2)));

// Barrier that waits only on LDS ops (global h_out stores are consumed by a
// later dispatch, never by another wave in-kernel -> no vmcnt drain).
#define LDS_BARRIER() asm volatile("s_waitcnt lgkmcnt(0)\n\ts_barrier" ::: "memory")

// f16 dot2: acc += a[0]*b[0] + a[1]*b[1]  (v_dot2_f32_f16)
#if __has_builtin(__builtin_amdgcn_fdot2)
#define FDOT2(acc, a, b) (acc) = __builtin_amdgcn_fdot2((a), (b), (acc), false)
#else
#define FDOT2(acc, a, b) asm("v_dot2_f32_f16 %0, %1, %2, %0" : "+v"(acc) : "v"(a), "v"(b))
#endif

// pack two f32 -> 2x f16 (v_cvt_pkrtz_f16_f32), bit-cast to our h2v type
__device__ __forceinline__ h2v pk_f16(float a, float b) {
    return __builtin_bit_cast(h2v, __builtin_amdgcn_cvt_pkrtz(a, b));
}

// intra-quad DPP exchange (ctrl is a compile-time immediate)
template <int CTRL>
__device__ __forceinline__ float dpp_mov(float x) {
    int r = __builtin_amdgcn_update_dpp(0, __builtin_bit_cast(int, x),
                                        CTRL, 0xF, 0xF, true);
    return __builtin_bit_cast(float, r);
}
// sum over the 4 lanes of a quad; all 4 lanes get the full sum
__device__ __forceinline__ float quad_sum(float x) {
    x += dpp_mov<0xB1>(x);   // quad_perm [1,0,3,2]
    x += dpp_mov<0x4E>(x);   // quad_perm [2,3,0,1]
    return x;
}

// ---------------------------------------------------------------------------
// Phase 1: GRU scan. 4 waves per sample (r14 structure — r15 proved TLP
// across samples only inflates per-block step time). Lane QUAD owns hidden
// unit (unit = w*16 + l>>2); kh = l&3 covers 16 K-elems. 29 pinned f16
// weight regs/lane; whole-sample Y staged to LDS f16; zero in-loop global
// loads; one LDS-only barrier per step.
// r16 change: TRANS-CHAIN OVERLAP — finish ar's quad-sum first and launch
// r's exp while the an/xn/az sums (DPP chains) still run; z's sigmoid
// overlaps nn's tanh. Math identical to r14.
// ---------------------------------------------------------------------------
__global__ __launch_bounds__(256, 1) void gru_kernel(
    const float* __restrict__ Y,     // (N,T,NO)
    const float* __restrict__ W_ih,  // (192,10)
    const float* __restrict__ W_hh,  // (192,64)
    const float* __restrict__ b_ih,
    const float* __restrict__ b_hh,
    float* __restrict__ h_out,       // (N*T,64)
    float* __restrict__ out)
{
    const int n    = blockIdx.x;
    const int tid  = threadIdx.x;    // 0..255
    const int w    = tid >> 6;       // wave 0..3
    const int l    = tid & 63;
    const int unit = w * 16 + (l >> 2);  // hidden unit 0..63
    const int kh   = l & 3;              // K quarter

    if (n == 0 && tid == 0)
        out[0] = 0.5f * (float)NS_ * (float)T_ * logf(2.f * 3.14159265358979323846f);

    // --- LDS: full-sample y (f16) + hidden state ---
    __shared__ __align__(16) h2v ylds[T_ * NO_ / 2];   // 5000 h2v = 20 KB
    __shared__ __align__(16) _Float16 hbuf[HID_];

    const float* Yn = Y + (size_t)n * T_ * NO_;
    // stage Y: coalesced float2 loads -> f16 pairs (row t = h2v [5t,5t+5))
    {
        const v2f* src = (const v2f*)Yn;
#pragma unroll 4
        for (int i = tid; i < T_ * NO_ / 2; i += 256) {
            v2f v = src[i];
            ylds[i] = pk_f16(v[0], v[1]);
        }
    }

    // --- W_hh: 3 gate rows, own K-quarter (16 f32 -> 8 h2v each) ---
    h2v whh[3][8];
#pragma unroll
    for (int g = 0; g < 3; ++g) {
        const v4f* wp = (const v4f*)(W_hh + (size_t)(g * HID_ + unit) * HID_ + kh * 16);
#pragma unroll
        for (int q = 0; q < 4; ++q) {
            v4f t = wp[q];
            whh[g][2 * q]     = pk_f16(t.x, t.y);
            whh[g][2 * q + 1] = pk_f16(t.z, t.w);
        }
    }
    // --- W_ih: full row of gate kh (kh==3: zero-scaled duplicate of gate 2) ---
    h2v wihx[5];
    {
        const float s = (kh == 3) ? 0.f : 1.f;
        const int gx = (kh < 3) ? kh : 2;
        const v2f* ip = (const v2f*)(W_ih + (size_t)(gx * HID_ + unit) * NO_);
#pragma unroll
        for (int i = 0; i < 5; ++i) { v2f t = ip[i]; wihx[i] = pk_f16(t[0] * s, t[1] * s); }
    }
    // VOLATILE pin: loads stay in the preamble, values stay resident.
#pragma unroll
    for (int g = 0; g < 3; ++g)
#pragma unroll
        for (int k = 0; k < 8; ++k) asm volatile("" : "+v"(whh[g][k]));
#pragma unroll
    for (int i = 0; i < 5; ++i) asm volatile("" : "+v"(wihx[i]));

    // x-routing masks (kh-fixed) and bias-folded accumulator inits
    const float mR = (kh == 0) ? 1.f : 0.f;
    const float mZ = (kh == 1) ? 1.f : 0.f;
    const float mN = (kh >= 2) ? 1.f : 0.f;
    const float cR = (kh == 0) ? (b_ih[unit] + b_hh[unit]) : 0.f;
    const float cZ = (kh == 0) ? (b_ih[HID_ + unit] + b_hh[HID_ + unit]) : 0.f;
    const float cN = (kh == 0) ? b_hh[2 * HID_ + unit] : 0.f;
    const float cX = (kh == 0) ? b_ih[2 * HID_ + unit] : 0.f;

    if (tid < HID_) hbuf[tid] = (_Float16)0.f;
    float h_own = 0.f;
    __syncthreads();   // staging + hbuf visible to all waves

    float* hout = h_out + (size_t)n * T_ * HID_ + unit;

    // prologue: y row 0 into registers (uniform LDS reads)
    h2v y0 = ylds[0], y1 = ylds[1], y2 = ylds[2], y3 = ylds[3], y4 = ylds[4];

    for (int t = 0; t < T_; ++t) {
        // x-projection from preloaded registers (overlaps hbuf read latency)
        float xs = 0.f;
        FDOT2(xs, wihx[0], y0); FDOT2(xs, wihx[1], y1); FDOT2(xs, wihx[2], y2);
        FDOT2(xs, wihx[3], y3); FDOT2(xs, wihx[4], y4);

        // h-projection: 2 uniform b128 reads of own K-quarter, 24 dot2.
        // ar's dots are issued FIRST so its quad-sum completes earliest.
        float ar = cR, az = cZ, an = cN, xn = cX;
        const uint4* hp = (const uint4*)(hbuf + kh * 16);
        uint4 hq0 = hp[0], hq1 = hp[1];
        h2v a0 = __builtin_bit_cast(h2v, hq0.x);
        h2v a1 = __builtin_bit_cast(h2v, hq0.y);
        h2v a2 = __builtin_bit_cast(h2v, hq0.z);
        h2v a3 = __builtin_bit_cast(h2v, hq0.w);
        h2v a4 = __builtin_bit_cast(h2v, hq1.x);
        h2v a5 = __builtin_bit_cast(h2v, hq1.y);
        h2v a6 = __builtin_bit_cast(h2v, hq1.z);
        h2v a7 = __builtin_bit_cast(h2v, hq1.w);
        // r-gate first (critical path: r -> tanh argument)
        FDOT2(ar, whh[0][0], a0); FDOT2(ar, whh[0][1], a1);
        FDOT2(ar, whh[0][2], a2); FDOT2(ar, whh[0][3], a3);
        FDOT2(ar, whh[0][4], a4); FDOT2(ar, whh[0][5], a5);
        FDOT2(ar, whh[0][6], a6); FDOT2(ar, whh[0][7], a7);
        ar = fmaf(xs, mR, ar);
        ar = quad_sum(ar);
        const float er = __expf(-ar);          // r's exp issues EARLY...
        // ...while n-gate dots + sums proceed underneath it
        FDOT2(an, whh[2][0], a0); FDOT2(an, whh[2][1], a1);
        FDOT2(an, whh[2][2], a2); FDOT2(an, whh[2][3], a3);
        FDOT2(an, whh[2][4], a4); FDOT2(an, whh[2][5], a5);
        FDOT2(an, whh[2][6], a6); FDOT2(an, whh[2][7], a7);
        xn = fmaf(xs, mN, xn);
        an = quad_sum(an);
        xn = quad_sum(xn);
        const float r = __builtin_amdgcn_rcpf(1.f + er);
        const float pre = xn + r * an;
        const float e2 = __expf(2.f * pre);    // tanh's exp issues...
        // ...while z-gate dots + sum proceed underneath it
        FDOT2(az, whh[1][0], a0); FDOT2(az, whh[1][1], a1);
        FDOT2(az, whh[1][2], a2); FDOT2(az, whh[1][3], a3);
        FDOT2(az, whh[1][4], a4); FDOT2(az, whh[1][5], a5);
        FDOT2(az, whh[1][6], a6); FDOT2(az, whh[1][7], a7);
        az = fmaf(xs, mZ, az);
        az = quad_sum(az);
        const float ez = __expf(-az);
        const float nn = 1.f - 2.f * __builtin_amdgcn_rcpf(e2 + 1.f);
        const float z  = __builtin_amdgcn_rcpf(1.f + ez);
        const float h_new = nn + z * (h_own - nn);
        h_own = h_new;
        if (kh == 0) {
            hbuf[unit] = (_Float16)h_new;   // next-step state (f16)
            hout[t * HID_] = h_new;         // fire-and-forget (f32)
        }
        // prefetch y row t+1 (uniform LDS reads; drained by barrier lgkmcnt)
        {
            const h2v* yrow = ylds + 5 * ((t + 1 < T_) ? t + 1 : t);
            y0 = yrow[0]; y1 = yrow[1]; y2 = yrow[2]; y3 = yrow[3]; y4 = yrow[4];
        }
        LDS_BARRIER();
    }
}

// ---------------------------------------------------------------------------
// Phase 2: per-(n,t) dense head + information-form Kalman + log-pdf terms.
// Each block computes A = H^T inv(C_w), M = A H redundantly (parallel GJ).
// ---------------------------------------------------------------------------
__global__ __launch_bounds__(256) void post_kernel(
    const float* __restrict__ h_out,  // (N*T,64)
    const float* __restrict__ Y,      // (N,T,NO)
    const float* __restrict__ X,      // (N,T,NS)
    const float* __restrict__ Hm, const float* __restrict__ C_w,
    const float* __restrict__ W_fc, const float* __restrict__ b_fc,
    const float* __restrict__ W_mean, const float* __restrict__ b_mean,
    const float* __restrict__ W_vars, const float* __restrict__ b_vars,
    float* __restrict__ out)
{
    __shared__ float sWfc[DENSE_][HID_];
    __shared__ float sWm[NS_][DENSE_];
    __shared__ float sWv[NS_][DENSE_];
    __shared__ float sA[NS_][NO_];
    __shared__ float sM[NS_][NS_];
    __shared__ float sbfc[DENSE_], sbm[NS_], sbv[NS_];
    __shared__ float wsum[4];
    __shared__ float W[NO_][2 * NO_];
    __shared__ float fcol[NO_];

    const int tid = threadIdx.x;

    // --- per-block A, M via parallel Gauss-Jordan on C_w (10x10 SPD) ---
    if (tid < NO_ * NO_) {
        const int i = tid / NO_, jj = tid % NO_;
        W[i][jj] = C_w[tid];
        W[i][NO_ + jj] = (i == jj) ? 1.f : 0.f;
    }
    __syncthreads();
    for (int p = 0; p < NO_; ++p) {
        const float ip = 1.f / W[p][p];
        __syncthreads();
        if (tid < 2 * NO_) W[p][tid] *= ip;
        __syncthreads();
        if (tid < NO_) fcol[tid] = (tid == p) ? 0.f : W[tid][p];
        __syncthreads();
        if (tid < NO_ * 2 * NO_) {
            const int i = tid / (2 * NO_), jj = tid % (2 * NO_);
            W[i][jj] -= fcol[i] * W[p][jj];
        }
        __syncthreads();
    }
    if (tid < NS_ * NO_) {
        const int s = tid / NO_, o = tid % NO_;
        float acc = 0.f;
        for (int p = 0; p < NO_; ++p) acc += Hm[p * NS_ + s] * W[p][NO_ + o];
        sA[s][o] = acc;
    }
    __syncthreads();
    if (tid < NS_ * NS_) {
        const int s = tid / NS_, q = tid % NS_;
        float acc = 0.f;
        for (int o = 0; o < NO_; ++o) acc += sA[s][o] * Hm[o * NS_ + q];
        sM[s][q] = acc;
    }

    // --- stage dense-head weights ---
    for (int i = tid; i < DENSE_ * HID_; i += blockDim.x)
        sWfc[i / HID_][i % HID_] = W_fc[i];
    for (int i = tid; i < NS_ * DENSE_; i += blockDim.x) {
        sWm[i / DENSE_][i % DENSE_] = W_mean[i];
        sWv[i / DENSE_][i % DENSE_] = W_vars[i];
    }
    if (tid < DENSE_) sbfc[tid] = b_fc[tid];
    if (tid < NS_) { sbm[tid] = b_mean[tid]; sbv[tid] = b_vars[tid]; }
    __syncthreads();

    const int task = blockIdx.x * blockDim.x + tid;
    float contrib = 0.f;
    if (task < N_ * T_) {
        float y[DENSE_];
#pragma unroll
        for (int d = 0; d < DENSE_; ++d) y[d] = sbfc[d];
        const float* hp = h_out + (size_t)task * HID_;
#pragma unroll
        for (int k = 0; k < HID_; k += 4) {
            float4 h4 = *(const float4*)(hp + k);
#pragma unroll
            for (int d = 0; d < DENSE_; ++d) {
                y[d] += sWfc[d][k + 0] * h4.x + sWfc[d][k + 1] * h4.y +
                        sWfc[d][k + 2] * h4.z + sWfc[d][k + 3] * h4.w;
            }
        }
#pragma unroll
        for (int d = 0; d < DENSE_; ++d) y[d] = fmaxf(y[d], 0.f);

        float mu[NS_], vinv[NS_];
#pragma unroll
        for (int s = 0; s < NS_; ++s) {
            float am = sbm[s], av = sbv[s];
#pragma unroll
            for (int d = 0; d < DENSE_; ++d) { am += sWm[s][d] * y[d]; av += sWv[s][d] * y[d]; }
            mu[s] = am;
            float sp = (av > 20.f) ? av : log1pf(__expf(av));  // softplus
            vinv[s] = 1.f / sp;
        }

        const float* yo = Y + (size_t)task * NO_;
        const float* xo = X + (size_t)task * NS_;
        float b[NS_];
#pragma unroll
        for (int s = 0; s < NS_; ++s) {
            float acc = vinv[s] * mu[s];
#pragma unroll
            for (int o = 0; o < NO_; ++o) acc += sA[s][o] * yo[o];
            b[s] = acc;
        }

        // L_inv = M + diag(v^-1), Cholesky
        float L[NS_][NS_];
#pragma unroll
        for (int i = 0; i < NS_; ++i)
#pragma unroll
            for (int jj = 0; jj <= i; ++jj)
                L[i][jj] = sM[i][jj] + ((i == jj) ? vinv[i] : 0.f);
        float ld = 0.f;
        float dinv[NS_];
#pragma unroll
        for (int jj = 0; jj < NS_; ++jj) {
            float s = L[jj][jj];
#pragma unroll
            for (int k = 0; k < jj; ++k) s -= L[jj][k] * L[jj][k];
            float d = sqrtf(s);
            ld += __logf(d);
            float di = 1.f / d;
            dinv[jj] = di;
            L[jj][jj] = d;
#pragma unroll
            for (int i = jj + 1; i < NS_; ++i) {
                float t2 = L[i][jj];
#pragma unroll
                for (int k = 0; k < jj; ++k) t2 -= L[i][k] * L[jj][k];
                L[i][jj] = t2 * di;
            }
        }
        ld *= 2.f;

        float w[NS_];
#pragma unroll
        for (int i = 0; i < NS_; ++i) {
            float s = b[i];
#pragma unroll
            for (int k = 0; k < i; ++k) s -= L[i][k] * w[k];
            w[i] = s * dinv[i];
        }
        float mpost[NS_];
#pragma unroll
        for (int ii = NS_ - 1; ii >= 0; --ii) {
            float s = w[ii];
#pragma unroll
            for (int k = ii + 1; k < NS_; ++k) s -= L[k][ii] * mpost[k];
            mpost[ii] = s * dinv[ii];
        }

        float diff[NS_];
#pragma unroll
        for (int s = 0; s < NS_; ++s) diff[s] = xo[s] - mpost[s];
        float quad = 0.f;
#pragma unroll
        for (int jj = 0; jj < NS_; ++jj) {
            float u = 0.f;
#pragma unroll
            for (int i = jj; i < NS_; ++i) u += L[i][jj] * diff[i];
            quad += u * u;
        }

        contrib = 0.5f * (ld - quad) * (1.0f / (float)N_);
    }

#pragma unroll
    for (int off = 32; off; off >>= 1) contrib += __shfl_down(contrib, off);
    const int wid = tid >> 6;
    if ((tid & 63) == 0) wsum[wid] = contrib;
    __syncthreads();
    if (tid == 0) {
        float s = 0.f;
#pragma unroll
        for (int i = 0; i < 4; ++i) s += wsum[i];
        atomicAdd(out, s);
    }
}

// ---------------------------------------------------------------------------
extern "C" void kernel_launch(void* const* d_in, const int* in_sizes, int n_in,
                              void* d_out, int out_size, void* d_ws, size_t ws_size,
                              hipStream_t stream)
{
    const float* Y      = (const float*)d_in[0];
    const float* X      = (const float*)d_in[1];
    const float* H      = (const float*)d_in[2];
    const float* C_w    = (const float*)d_in[4];
    const float* W_ih   = (const float*)d_in[5];
    const float* W_hh   = (const float*)d_in[6];
    const float* b_ih   = (const float*)d_in[7];
    const float* b_hh   = (const float*)d_in[8];
    const float* W_fc   = (const float*)d_in[9];
    const float* b_fc   = (const float*)d_in[10];
    const float* W_mean = (const float*)d_in[11];
    const float* b_mean = (const float*)d_in[12];
    const float* W_vars = (const float*)d_in[13];
    const float* b_vars = (const float*)d_in[14];
    float* out = (float*)d_out;

    float* h_out = (float*)d_ws;                       // 32.77 MB

    hipLaunchKernelGGL(gru_kernel, dim3(N_), dim3(256), 0, stream,
                       Y, W_ih, W_hh, b_ih, b_hh, h_out, out);
    hipLaunchKernelGGL(post_kernel, dim3((N_ * T_ + 255) / 256), dim3(256), 0, stream,
                       h_out, Y, X, H, C_w, W_fc, b_fc, W_mean, b_mean,
                       W_vars, b_vars, out);
}